// Round 4
// baseline (299.926 us; speedup 1.0000x reference)
//
#include <hip/hip_runtime.h>

#define N_TOK 65536
#define DIM   256
#define K_CODES 1024
#define CB_OFF    16777216                    // N_TOK*DIM
#define PROBS_OFF (16777216 + 262144)
#define LOSS_OFF  (16777216 + 262144 + 1024)
#define TM 64                                 // tokens per k_main tile
#define NBLK (N_TOK / TM)                     // 1024 tiles
#define TPASS 4                               // tiles per persistent block
#define GRID_MAIN (NBLK / TPASS)              // 256 blocks

typedef float  f32x4  __attribute__((ext_vector_type(4)));
typedef short  s16x8  __attribute__((ext_vector_type(8)));

__device__ __forceinline__ unsigned short f32_to_bf16(float x) {
    unsigned u = __float_as_uint(x);
    unsigned r = (u + 0x7FFFu + ((u >> 16) & 1u)) >> 16;
    return (unsigned short)r;
}
// monotone uint key for float MAX-reduction (no NaNs here)
__device__ __forceinline__ unsigned fkey(float a) {
    unsigned u = __float_as_uint(a);
    unsigned m = (unsigned)(((int)u) >> 31);
    return u ^ (m | 0x80000000u);
}
__device__ __forceinline__ float fkey_inv(unsigned k) {
    unsigned u = (k & 0x80000000u) ? (k ^ 0x80000000u) : ~k;
    return __uint_as_float(u);
}

// ---- 16-lane row reductions via DPP (VALU, no DS traffic) -----------------
__device__ __forceinline__ unsigned red16_max_u(unsigned v) {
    unsigned t;
    t = (unsigned)__builtin_amdgcn_update_dpp(0, (int)v, 0xB1,  0xF, 0xF, true); v = v > t ? v : t;
    t = (unsigned)__builtin_amdgcn_update_dpp(0, (int)v, 0x4E,  0xF, 0xF, true); v = v > t ? v : t;
    t = (unsigned)__builtin_amdgcn_update_dpp(0, (int)v, 0x141, 0xF, 0xF, true); v = v > t ? v : t;
    t = (unsigned)__builtin_amdgcn_update_dpp(0, (int)v, 0x140, 0xF, 0xF, true); v = v > t ? v : t;
    return v;
}
__device__ __forceinline__ float red16_sum_f(float v) {
    float t;
    t = __uint_as_float((unsigned)__builtin_amdgcn_update_dpp(0, (int)__float_as_uint(v), 0xB1,  0xF, 0xF, true)); v += t;
    t = __uint_as_float((unsigned)__builtin_amdgcn_update_dpp(0, (int)__float_as_uint(v), 0x4E,  0xF, 0xF, true)); v += t;
    t = __uint_as_float((unsigned)__builtin_amdgcn_update_dpp(0, (int)__float_as_uint(v), 0x141, 0xF, 0xF, true)); v += t;
    t = __uint_as_float((unsigned)__builtin_amdgcn_update_dpp(0, (int)__float_as_uint(v), 0x140, 0xF, 0xF, true)); v += t;
    return v;
}

// zstage swizzle: float-index XOR spreading 16 rows over 16 distinct 16B slots
// (rows 0..15 -> byte offsets 0,32,..224 and 16,48,..240 -> 2 lanes/bank, free).
__device__ __forceinline__ int zswz(int row) {
    return (((row) & 7) << 3) | ((((row) >> 3) & 1) << 2);
}
// HBM -> LDS direct (16B/lane, no VGPR round-trip). lds ptr must be wave-uniform.
__device__ __forceinline__ void gl_lds16(const float* gp, float* lp) {
    __builtin_amdgcn_global_load_lds(
        (const __attribute__((address_space(1))) unsigned int*)gp,
        (__attribute__((address_space(3))) unsigned int*)lp, 16, 0, 0);
}
// stage one 64x256 fp32 tile into zstage (swizzled via pre-permuted global src).
__device__ __forceinline__ void stage_tile(const float* zg, float* zstage, int w, int ln) {
    #pragma unroll
    for (int s = 0; s < 4; s++) {
        const int j = s * 16 + w;          // row j of the tile (1KB per instruction)
        gl_lds16(zg + j * 256 + ((ln * 4) ^ zswz(j)), &zstage[j * 256]);
    }
}

// ---------------- K0: codebook -> bf16 frag-layout scratch + c2 + zero accs (+fp32 copy) ----
__global__ __launch_bounds__(512) void k_prep(const float* __restrict__ cb,
                                              float* __restrict__ c2,
                                              unsigned short* __restrict__ cbf,
                                              float* __restrict__ probs_part,
                                              float* __restrict__ lossR,
                                              float* __restrict__ outcb,
                                              int zcount, int nloss, int docopy) {
    const int g  = blockIdx.x;
    const int t  = threadIdx.x;
    const int wv = t >> 6;
    const int ln = t & 63;
    const int l15 = ln & 15, q = ln >> 4;

    const float* zp = cb + (size_t)(g * 16 + l15) * DIM + wv * 32 + q * 8;
    f32x4 z0 = *(const f32x4*)(zp);
    f32x4 z1 = *(const f32x4*)(zp + 4);
    s16x8 a;
    a[0] = (short)f32_to_bf16(z0[0]); a[1] = (short)f32_to_bf16(z0[1]);
    a[2] = (short)f32_to_bf16(z0[2]); a[3] = (short)f32_to_bf16(z0[3]);
    a[4] = (short)f32_to_bf16(z1[0]); a[5] = (short)f32_to_bf16(z1[1]);
    a[6] = (short)f32_to_bf16(z1[2]); a[7] = (short)f32_to_bf16(z1[3]);
    *(s16x8*)(cbf + (size_t)(g * 8 + wv) * 512 + ln * 8) = a;

    float s = z0[0]*z0[0] + z0[1]*z0[1] + z0[2]*z0[2] + z0[3]*z0[3]
            + z1[0]*z1[0] + z1[1]*z1[1] + z1[2]*z1[2] + z1[3]*z1[3];
    s += __shfl_xor(s, 16, 64);
    s += __shfl_xor(s, 32, 64);
    __shared__ float c2p[8][16];
    if (q == 0) c2p[wv][l15] = s;

    // accumulator zeroing / page pre-touch + optional fp32 codebook copy
    const int base = g * 512 + t;          // 0 .. 32767
    if (base < nloss) lossR[base] = 0.f;
    if (zcount >= 0) {
        if (base < zcount) probs_part[base] = 0.f;
        if (base + 32768 < zcount) probs_part[base + 32768] = 0.f;
    } else {
        if (base < -zcount) probs_part[(size_t)base * 1024] = 0.f;  // 1 word / 4KB page
    }
    if (docopy) {
        #pragma unroll
        for (int i = 0; i < 8; i++) outcb[base + i * 32768] = cb[base + i * 32768];
    }

    __syncthreads();
    if (t < 16) {
        float acc = 0.f;
        #pragma unroll
        for (int ww = 0; ww < 8; ww++) acc += c2p[ww][t];
        c2[g * 16 + t] = acc;
    }
}

// ---------------- K1: persistent fused distances + argmin + softmax + gather + loss -----
// 256 blocks x 1024 threads (16 waves), TPASS=4 tiles of 64 tokens each.
// Next tile's z-slab (64KB fp32) is DMA'd HBM->LDS (global_load_lds, swizzled source)
// during the current tile's K-loop + epilogue; between tiles only a short LDS->LDS
// bf16 convert remains. Wave w owns codes [64w,64w+64); acc[4][4] = 64 f32/thread.
__global__ __launch_bounds__(1024, 4) void k_main(const float* __restrict__ z,
                                                  const float* __restrict__ cb,
                                                  const unsigned short* __restrict__ cbf,
                                                  const float* __restrict__ c2,
                                                  float* __restrict__ out_q,
                                                  float* __restrict__ probs_part,
                                                  float* __restrict__ lossR,
                                                  int repmask) {
    const int t   = threadIdx.x;
    const int w   = t >> 6;       // wave 0..15
    const int ln  = t & 63;
    const int q   = ln >> 4;
    const int l15 = ln & 15;
    const int k0  = w * 64;

    __shared__ float zstage[TM * DIM];              // 64 KB fp32 staging (swizzled)
    __shared__ unsigned short a_lds[32 * 64 * 8];   // 32 KB bf16 fragments
    __shared__ float    z2p[32][16];                // z2 partials: [m*8+ds][row16]
    __shared__ unsigned kred[16][64];
    __shared__ float    ered[16][64];
    __shared__ int   fidx[64];
    __shared__ float fU[64];

    // persistent setup: c2 and B base loaded once
    float c2v[4];
    #pragma unroll
    for (int nt = 0; nt < 4; nt++) c2v[nt] = c2[k0 + nt * 16 + l15];
    const unsigned short* bb = cbf + (size_t)(w * 4) * 8 * 512 + ln * 8;
    float loss_acc = 0.f;

    // prefetch tile 0
    stage_tile(z + (size_t)blockIdx.x * TM * DIM, zstage, w, ln);

    for (int p = 0; p < TPASS; p++) {
        const int tile = blockIdx.x + p * GRID_MAIN;
        const int n0   = tile * TM;
        float* pp = probs_part +
            (size_t)((repmask < 0) ? tile : (tile & repmask)) * K_CODES;

        // wait own staging loads (+ drains prior stores), then block-wide sync
        asm volatile("s_waitcnt vmcnt(0)" ::: "memory");
        __syncthreads();

        // ---- convert: zstage(fp32,swizzled) -> a_lds(bf16 frags) + z2 partials ----
        #pragma unroll
        for (int rep = 0; rep < 2; rep++) {
            const int md  = w + rep * 16;      // = m*8 + ds
            const int m   = md >> 3;
            const int dsv = md & 7;
            const int row = m * 16 + l15;
            const int dim = dsv * 32 + q * 8;
            const int sw  = zswz(row);
            const float* zp = zstage + row * 256;
            f32x4 z0 = *(const f32x4*)(zp + (dim ^ sw));
            f32x4 z1 = *(const f32x4*)(zp + ((dim + 4) ^ sw));
            s16x8 a;
            a[0] = (short)f32_to_bf16(z0[0]); a[1] = (short)f32_to_bf16(z0[1]);
            a[2] = (short)f32_to_bf16(z0[2]); a[3] = (short)f32_to_bf16(z0[3]);
            a[4] = (short)f32_to_bf16(z1[0]); a[5] = (short)f32_to_bf16(z1[1]);
            a[6] = (short)f32_to_bf16(z1[2]); a[7] = (short)f32_to_bf16(z1[3]);
            *(s16x8*)(a_lds + (size_t)(md * 64 + ln) * 8) = a;
            float s = z0[0]*z0[0] + z0[1]*z0[1] + z0[2]*z0[2] + z0[3]*z0[3]
                    + z1[0]*z1[0] + z1[1]*z1[1] + z1[2]*z1[2] + z1[3]*z1[3];
            s += __shfl_xor(s, 16, 64);
            s += __shfl_xor(s, 32, 64);
            if (q == 0) z2p[md][l15] = s;      // single writer
        }

        // acc init: -0.5*c2[col]  (then s = -2*acc after MFMA)
        f32x4 acc[4][4];
        #pragma unroll
        for (int m = 0; m < 4; m++)
            #pragma unroll
            for (int nt = 0; nt < 4; nt++) {
                const float iv = -0.5f * c2v[nt];
                f32x4 v4 = {iv, iv, iv, iv};
                acc[m][nt] = v4;
            }

        __syncthreads();

        // issue async prefetch of the NEXT tile (flies under K-loop + epilogue)
        if (p + 1 < TPASS)
            stage_tile(z + (size_t)(blockIdx.x + (p + 1) * GRID_MAIN) * TM * DIM,
                       zstage, w, ln);

        // ---- K loop: 8 steps of 32 dims, 16 MFMA per 4 B-loads ----
        #pragma unroll
        for (int ds = 0; ds < 8; ds++) {
            s16x8 af[4];
            #pragma unroll
            for (int m = 0; m < 4; m++)
                af[m] = *(const s16x8*)(a_lds + (size_t)((m * 8 + ds) * 64 + ln) * 8);
            #pragma unroll
            for (int nt = 0; nt < 4; nt++) {
                s16x8 b = *(const s16x8*)(bb + (size_t)(nt * 8 + ds) * 512);
                #pragma unroll
                for (int m = 0; m < 4; m++)
                    acc[m][nt] = __builtin_amdgcn_mfma_f32_16x16x32_bf16(af[m], b, acc[m][nt], 0, 0, 0);
            }
        }

        // ---- epilogue: packed-key argmax(acc) (= argmin s), expsum; e -> acc ----
        unsigned lkey[4][4];
        float    lesum[4][4];
        #pragma unroll
        for (int m = 0; m < 4; m++)
            #pragma unroll
            for (int v = 0; v < 4; v++) { lkey[m][v] = 0u; lesum[m][v] = 0.f; }

        #pragma unroll
        for (int m = 0; m < 4; m++)
            #pragma unroll
            for (int nt = 0; nt < 4; nt++) {
                const unsigned colc = 1023u - (unsigned)(k0 + nt * 16 + l15);
                #pragma unroll
                for (int v = 0; v < 4; v++) {
                    float a = acc[m][nt][v];
                    unsigned key = (fkey(a) & 0xFFFFFC00u) | colc;
                    lkey[m][v] = max(lkey[m][v], key);
                    float e = __expf(a + a);          // exp(-s) = exp(2a)
                    acc[m][nt][v] = e;
                    lesum[m][v] += e;
                }
            }

        // cross-lane within 16-lane row slice -- DPP on VALU
        #pragma unroll
        for (int m = 0; m < 4; m++)
            #pragma unroll
            for (int v = 0; v < 4; v++) {
                lkey[m][v]  = red16_max_u(lkey[m][v]);
                lesum[m][v] = red16_sum_f(lesum[m][v]);
            }

        // cross-wave combine (16 waves) through LDS
        if (l15 == 0) {
            #pragma unroll
            for (int m = 0; m < 4; m++)
                #pragma unroll
                for (int v = 0; v < 4; v++) {
                    const int r = m * 16 + q * 4 + v;
                    kred[w][r] = lkey[m][v]; ered[w][r] = lesum[m][v];
                }
        }
        __syncthreads();
        if (t < 64) {
            unsigned bk = kred[0][t];
            float U = ered[0][t];
            #pragma unroll
            for (int ww = 1; ww < 16; ww++) {
                bk = max(bk, kred[ww][t]);
                U += ered[ww][t];
            }
            fidx[t] = 1023 - (int)(bk & 1023u);
            fU[t] = U;
            float a_rec = fkey_inv(bk);        // quantized a; s_min = -2a
            float z2 = 0.f;
            #pragma unroll
            for (int ds = 0; ds < 8; ds++) z2 += z2p[(t >> 4) * 8 + ds][t & 15];
            loss_acc += z2 - 2.0f * a_rec;     // ||z-q||^2 = ||z||^2 + s_min
        }
        __syncthreads();

        // probs: column sums of e/U over the tile's 64 rows
        float ps[4];
        #pragma unroll
        for (int nt = 0; nt < 4; nt++) ps[nt] = 0.f;
        #pragma unroll
        for (int m = 0; m < 4; m++)
            #pragma unroll
            for (int v = 0; v < 4; v++) {
                const float invU = 1.0f / fU[m * 16 + q * 4 + v];
                #pragma unroll
                for (int nt = 0; nt < 4; nt++) ps[nt] += acc[m][nt][v] * invU;
            }
        #pragma unroll
        for (int nt = 0; nt < 4; nt++) {
            ps[nt] += __shfl_xor(ps[nt], 16, 64);
            ps[nt] += __shfl_xor(ps[nt], 32, 64);
        }
        if (repmask < 0) pp[k0 + q * 16 + l15] = ps[q];          // store mode
        else             atomicAdd(&pp[k0 + q * 16 + l15], ps[q]);

        // quantized gather + store: wave w handles rows [4w, 4w+4)
        #pragma unroll
        for (int i = 0; i < 4; i++) {
            const int r  = w * 4 + i;
            const int am = fidx[r];
            f32x4 qv = *(const f32x4*)(cb + (size_t)am * DIM + ln * 4);
            *(f32x4*)(out_q + (size_t)(n0 + r) * DIM + ln * 4) = qv;
        }
    }

    // loss: one atomic per block (wave 0 holds per-row terms)
    if (w == 0) {
        #pragma unroll
        for (int off = 32; off; off >>= 1) loss_acc += __shfl_down(loss_acc, off, 64);
        if (ln == 0) atomicAdd(&lossR[blockIdx.x & 63], loss_acc);
    }
}

// ---------------- K2: (optional codebook copy), probs reduce+mean+clip, vq_loss ----------------
__global__ __launch_bounds__(1024) void k_fin(const float* __restrict__ cb,
                                              const float* __restrict__ probs_part,
                                              const float* __restrict__ lossR,
                                              float* __restrict__ out,
                                              int R, int nLoss, int docopy) {
    const int t = threadIdx.x;
    const int g = blockIdx.x * 1024 + t;
    __shared__ float part[16][64];
    if (docopy && g < 262144) out[CB_OFF + g] = cb[g];
    if (R >= NBLK) {
        if (blockIdx.x < 16) {
            const int w  = t >> 6;
            const int ln = t & 63;
            const int col = blockIdx.x * 64 + ln;
            const float* p0 = probs_part + (size_t)(w * 64) * K_CODES + col;
            float a0 = 0.f, a1 = 0.f, a2 = 0.f, a3 = 0.f;
            #pragma unroll 4
            for (int r = 0; r < 64; r += 4) {
                a0 += p0[(size_t)(r + 0) * K_CODES];
                a1 += p0[(size_t)(r + 1) * K_CODES];
                a2 += p0[(size_t)(r + 2) * K_CODES];
                a3 += p0[(size_t)(r + 3) * K_CODES];
            }
            part[w][ln] = a0 + a1 + a2 + a3;
            __syncthreads();
            if (t < 64) {
                float p = 0.f;
                #pragma unroll
                for (int ww = 0; ww < 16; ww++) p += part[ww][t];
                p *= (1.0f / 65536.0f);
                p = fminf(fmaxf(p, 0.001f), 0.999f);
                out[PROBS_OFF + blockIdx.x * 64 + t] = p;
            }
        }
    } else if (g < K_CODES) {
        float a0 = 0.f, a1 = 0.f, a2 = 0.f, a3 = 0.f;
        if (R >= 4) {
            for (int r = 0; r < R; r += 4) {
                a0 += probs_part[(r + 0) * K_CODES + g];
                a1 += probs_part[(r + 1) * K_CODES + g];
                a2 += probs_part[(r + 2) * K_CODES + g];
                a3 += probs_part[(r + 3) * K_CODES + g];
            }
        } else {
            for (int r = 0; r < R; r++) a0 += probs_part[r * K_CODES + g];
        }
        float p = (a0 + a1 + a2 + a3) * (1.0f / 65536.0f);
        p = fminf(fmaxf(p, 0.001f), 0.999f);
        out[PROBS_OFF + g] = p;
    }
    if (g == 0) {
        float ls = 0.f;
        for (int r = 0; r < nLoss; r++) ls += lossR[r];
        out[LOSS_OFF] = ls * (1280.0f / 16777216.0f);   // 1.25*1024/(65536*256)
    }
}

extern "C" void kernel_launch(void* const* d_in, const int* in_sizes, int n_in,
                              void* d_out, int out_size, void* d_ws, size_t ws_size,
                              hipStream_t stream) {
    (void)in_sizes; (void)n_in; (void)out_size;
    const float* z  = (const float*)d_in[0];
    const float* cb = (const float*)d_in[1];
    float* out = (float*)d_out;

    float* c2 = (float*)d_ws;                 // 1024 floats

    // probs replicas: R=NBLK (store mode, no atomics) preferred; else atomic tiers.
    float *probs_part, *lossR;
    int R, nLoss, repmask;
    size_t used = 1024 * 4;
    auto fits = [&](int r) { return ws_size >= used + (size_t)(64 + r * 1024) * 4; };
    if      (fits(NBLK)) R = NBLK;
    else if (fits(64))   R = 64;
    else if (fits(16))   R = 16;
    else if (fits(4))    R = 4;
    else                 R = 0;
    const int storeMode = (R == NBLK);
    if (R) {
        lossR      = c2 + 1024;
        probs_part = lossR + 64;
        nLoss = 64;
        used += (size_t)(64 + (size_t)R * 1024) * 4;
        repmask = storeMode ? -1 : (R - 1);
    } else {
        probs_part = out + PROBS_OFF;
        lossR      = out + LOSS_OFF;
        R = 1; nLoss = 1; repmask = 0;
    }

    // bf16 frag-layout codebook (dense, 512 KB): ws if it fits (then k_prep writes the
    // fp32 copy), else in out's codebook region (then k_fin rewrites it with fp32).
    unsigned short* cbf;
    int cbf_in_ws = (ws_size >= used + (size_t)K_CODES * DIM * 2);
    if (cbf_in_ws) cbf = (unsigned short*)((char*)d_ws + used);
    else           cbf = (unsigned short*)(out + CB_OFF);

    k_prep<<<dim3(64), dim3(512), 0, stream>>>(cb, c2, cbf, probs_part, lossR,
                                               out + CB_OFF, storeMode ? -NBLK : R * 1024,
                                               nLoss, cbf_in_ws);
    k_main<<<dim3(GRID_MAIN), dim3(1024), 0, stream>>>(z, cb, cbf, c2, out, probs_part,
                                                       lossR, repmask);
    const int fin_blocks = (!cbf_in_ws) ? 256 : (storeMode ? 16 : 1);
    k_fin<<<dim3(fin_blocks), dim3(1024), 0, stream>>>(cb, probs_part, lossR, out,
                                                       R, nLoss, !cbf_in_ws);
}

// Round 5
// 189.718 us; speedup vs baseline: 1.5809x; 1.5809x over previous
//
#include <hip/hip_runtime.h>

#define N_TOK 65536
#define DIM   256
#define K_CODES 1024
#define CB_OFF    16777216                    // N_TOK*DIM
#define PROBS_OFF (16777216 + 262144)
#define LOSS_OFF  (16777216 + 262144 + 1024)
#define TM 64                                 // tokens per k_main block
#define NBLK (N_TOK / TM)                     // 1024

typedef float  f32x4  __attribute__((ext_vector_type(4)));
typedef short  s16x8  __attribute__((ext_vector_type(8)));

__device__ __forceinline__ unsigned short f32_to_bf16(float x) {
    unsigned u = __float_as_uint(x);
    unsigned r = (u + 0x7FFFu + ((u >> 16) & 1u)) >> 16;
    return (unsigned short)r;
}
// monotone uint key for float MAX-reduction (no NaNs here)
__device__ __forceinline__ unsigned fkey(float a) {
    unsigned u = __float_as_uint(a);
    unsigned m = (unsigned)(((int)u) >> 31);
    return u ^ (m | 0x80000000u);
}
__device__ __forceinline__ float fkey_inv(unsigned k) {
    unsigned u = (k & 0x80000000u) ? (k ^ 0x80000000u) : ~k;
    return __uint_as_float(u);
}

// ---- 16-lane row reductions via DPP (VALU, no DS traffic) -----------------
// hops: xor1 (quad_perm 0xB1), xor2 (quad_perm 0x4E), row_half_mirror (0x141),
// row_mirror (0x140). After the first two hops each quad is uniform, so the
// mirrors combine quad-pairs exactly like xor4/xor8.
__device__ __forceinline__ unsigned red16_max_u(unsigned v) {
    unsigned t;
    t = (unsigned)__builtin_amdgcn_update_dpp(0, (int)v, 0xB1,  0xF, 0xF, true); v = v > t ? v : t;
    t = (unsigned)__builtin_amdgcn_update_dpp(0, (int)v, 0x4E,  0xF, 0xF, true); v = v > t ? v : t;
    t = (unsigned)__builtin_amdgcn_update_dpp(0, (int)v, 0x141, 0xF, 0xF, true); v = v > t ? v : t;
    t = (unsigned)__builtin_amdgcn_update_dpp(0, (int)v, 0x140, 0xF, 0xF, true); v = v > t ? v : t;
    return v;
}
__device__ __forceinline__ float red16_sum_f(float v) {
    float t;
    t = __uint_as_float((unsigned)__builtin_amdgcn_update_dpp(0, (int)__float_as_uint(v), 0xB1,  0xF, 0xF, true)); v += t;
    t = __uint_as_float((unsigned)__builtin_amdgcn_update_dpp(0, (int)__float_as_uint(v), 0x4E,  0xF, 0xF, true)); v += t;
    t = __uint_as_float((unsigned)__builtin_amdgcn_update_dpp(0, (int)__float_as_uint(v), 0x141, 0xF, 0xF, true)); v += t;
    t = __uint_as_float((unsigned)__builtin_amdgcn_update_dpp(0, (int)__float_as_uint(v), 0x140, 0xF, 0xF, true)); v += t;
    return v;
}

// ---------------- K0: codebook -> bf16 frag-layout scratch + c2 + zero accs (+fp32 copy) ----
// Block g (64 blocks, 512 thr) handles code group g (16 codes). Frag (n-tile g, ds=wv)
// at cbf[(g*8+wv)*1024 + ln*8] (sparse 1024-short stride — r1's measured-94µs layout).
// zcount >= 0: zero probs_part[0..zcount). zcount < 0: page-touch -zcount pages (store mode).
__global__ __launch_bounds__(512) void k_prep(const float* __restrict__ cb,
                                              float* __restrict__ c2,
                                              unsigned short* __restrict__ cbf,
                                              float* __restrict__ probs_part,
                                              float* __restrict__ lossR,
                                              float* __restrict__ outcb,
                                              int zcount, int nloss, int docopy) {
    const int g  = blockIdx.x;
    const int t  = threadIdx.x;
    const int wv = t >> 6;
    const int ln = t & 63;
    const int l15 = ln & 15, q = ln >> 4;

    const float* zp = cb + (size_t)(g * 16 + l15) * DIM + wv * 32 + q * 8;
    f32x4 z0 = *(const f32x4*)(zp);
    f32x4 z1 = *(const f32x4*)(zp + 4);
    s16x8 a;
    a[0] = (short)f32_to_bf16(z0[0]); a[1] = (short)f32_to_bf16(z0[1]);
    a[2] = (short)f32_to_bf16(z0[2]); a[3] = (short)f32_to_bf16(z0[3]);
    a[4] = (short)f32_to_bf16(z1[0]); a[5] = (short)f32_to_bf16(z1[1]);
    a[6] = (short)f32_to_bf16(z1[2]); a[7] = (short)f32_to_bf16(z1[3]);
    *(s16x8*)(cbf + (size_t)(g * 8 + wv) * 1024 + ln * 8) = a;

    float s = z0[0]*z0[0] + z0[1]*z0[1] + z0[2]*z0[2] + z0[3]*z0[3]
            + z1[0]*z1[0] + z1[1]*z1[1] + z1[2]*z1[2] + z1[3]*z1[3];
    s += __shfl_xor(s, 16, 64);
    s += __shfl_xor(s, 32, 64);
    __shared__ float c2p[8][16];
    if (q == 0) c2p[wv][l15] = s;

    // accumulator zeroing / page pre-touch + optional fp32 codebook copy
    const int base = g * 512 + t;          // 0 .. 32767
    if (base < nloss) lossR[base] = 0.f;
    if (zcount >= 0) {
        if (base < zcount) probs_part[base] = 0.f;
        if (base + 32768 < zcount) probs_part[base + 32768] = 0.f;
    } else {
        if (base < -zcount) probs_part[(size_t)base * 1024] = 0.f;  // 1 word / 4KB page
    }
    if (docopy) {
        #pragma unroll
        for (int i = 0; i < 8; i++) outcb[base + i * 32768] = cb[base + i * 32768];
    }

    __syncthreads();
    if (t < 16) {
        float acc = 0.f;
        #pragma unroll
        for (int ww = 0; ww < 8; ww++) acc += c2p[ww][t];
        c2[g * 16 + t] = acc;
    }
}

// ---------------- K1: fused distances + argmin + softmax + gather + loss ----------------
// r1's measured-94µs kernel, verbatim. 1024 threads (16 waves), 64 tokens/block,
// grid 1024. Wave w owns codes [64w, 64w+64); acc[4][4] = 64 f32/thread (exactly the
// 128-reg budget with the 64 arch VGPRs — do NOT add live state across the K-loop).
// repmask >= 0: atomic accumulation into replica (blockIdx & repmask).
// repmask <  0: store mode -- each block writes its OWN replica row blockIdx.x.
__global__ __launch_bounds__(1024, 4) void k_main(const float* __restrict__ z,
                                                  const float* __restrict__ cb,
                                                  const unsigned short* __restrict__ cbf,
                                                  const float* __restrict__ c2,
                                                  float* __restrict__ out_q,
                                                  float* __restrict__ probs_part,
                                                  float* __restrict__ lossR,
                                                  int repmask) {
    const int t   = threadIdx.x;
    const int w   = t >> 6;       // wave 0..15
    const int ln  = t & 63;
    const int q   = ln >> 4;
    const int l15 = ln & 15;
    const int k0  = w * 64;
    const int n0  = blockIdx.x * TM;
    float* pp = probs_part +
        (size_t)((repmask < 0) ? (int)blockIdx.x : (int)(blockIdx.x & repmask)) * K_CODES;

    __shared__ unsigned short a_lds[32 * 64 * 8];   // 32 KB, frag f=(m*8+ds)*64+ln at a_lds[f*8]
    __shared__ float    z2p[32][16];                // z2 partials: [m*8+ds][row16]
    __shared__ unsigned kred[16][64];
    __shared__ float    ered[16][64];
    __shared__ int   fidx[64];
    __shared__ float fU[64];

    // ---- phase 0: cooperative A fill (fp32 -> bf16, fragment order) + z2 partials ----
    #pragma unroll
    for (int rep = 0; rep < 2; rep++) {
        const int f   = t + rep * 1024;
        const int md  = w + rep * 16;      // = m*8 + ds
        const int m   = md >> 3;
        const int dsv = md & 7;
        const int row = m * 16 + l15;
        const int dim = dsv * 32 + q * 8;
        const float* zp = z + (size_t)(n0 + row) * DIM + dim;
        f32x4 z0 = *(const f32x4*)(zp);
        f32x4 z1 = *(const f32x4*)(zp + 4);
        s16x8 a;
        a[0] = (short)f32_to_bf16(z0[0]); a[1] = (short)f32_to_bf16(z0[1]);
        a[2] = (short)f32_to_bf16(z0[2]); a[3] = (short)f32_to_bf16(z0[3]);
        a[4] = (short)f32_to_bf16(z1[0]); a[5] = (short)f32_to_bf16(z1[1]);
        a[6] = (short)f32_to_bf16(z1[2]); a[7] = (short)f32_to_bf16(z1[3]);
        *(s16x8*)(a_lds + (size_t)f * 8) = a;
        float s = z0[0]*z0[0] + z0[1]*z0[1] + z0[2]*z0[2] + z0[3]*z0[3]
                + z1[0]*z1[0] + z1[1]*z1[1] + z1[2]*z1[2] + z1[3]*z1[3];
        s += __shfl_xor(s, 16, 64);
        s += __shfl_xor(s, 32, 64);
        if (q == 0) z2p[md][l15] = s;      // single writer
    }

    // acc init: -0.5*c2[col]  (then s = -2*acc after MFMA)
    float c2v[4];
    #pragma unroll
    for (int nt = 0; nt < 4; nt++) c2v[nt] = c2[k0 + nt * 16 + l15];
    f32x4 acc[4][4];
    #pragma unroll
    for (int m = 0; m < 4; m++)
        #pragma unroll
        for (int nt = 0; nt < 4; nt++) {
            const float iv = -0.5f * c2v[nt];
            f32x4 v4 = {iv, iv, iv, iv};
            acc[m][nt] = v4;
        }

    __syncthreads();

    // ---- K loop: 8 steps of 32 dims, 16 MFMA per 4 B-loads ----
    const unsigned short* bb = cbf + (size_t)(w * 4) * 8 * 1024 + ln * 8;
    #pragma unroll
    for (int ds = 0; ds < 8; ds++) {
        s16x8 af[4];
        #pragma unroll
        for (int m = 0; m < 4; m++)
            af[m] = *(const s16x8*)(a_lds + (size_t)((m * 8 + ds) * 64 + ln) * 8);
        #pragma unroll
        for (int nt = 0; nt < 4; nt++) {
            s16x8 b = *(const s16x8*)(bb + (size_t)(nt * 8 + ds) * 1024);
            #pragma unroll
            for (int m = 0; m < 4; m++)
                acc[m][nt] = __builtin_amdgcn_mfma_f32_16x16x32_bf16(af[m], b, acc[m][nt], 0, 0, 0);
        }
    }

    // ---- epilogue: packed-key argmax(acc) (= argmin s), expsum; e -> acc ----
    unsigned lkey[4][4];
    float    lesum[4][4];
    #pragma unroll
    for (int m = 0; m < 4; m++)
        #pragma unroll
        for (int v = 0; v < 4; v++) { lkey[m][v] = 0u; lesum[m][v] = 0.f; }

    #pragma unroll
    for (int m = 0; m < 4; m++)
        #pragma unroll
        for (int nt = 0; nt < 4; nt++) {
            const unsigned colc = 1023u - (unsigned)(k0 + nt * 16 + l15);  // ties -> lowest col
            #pragma unroll
            for (int v = 0; v < 4; v++) {
                float a = acc[m][nt][v];
                unsigned key = (fkey(a) & 0xFFFFFC00u) | colc;
                lkey[m][v] = max(lkey[m][v], key);
                float e = __expf(a + a);          // exp(-s) = exp(2a), z2 row-const cancels in e/U
                acc[m][nt][v] = e;
                lesum[m][v] += e;
            }
        }

    // cross-lane within 16-lane row slice -- DPP on VALU
    #pragma unroll
    for (int m = 0; m < 4; m++)
        #pragma unroll
        for (int v = 0; v < 4; v++) {
            lkey[m][v]  = red16_max_u(lkey[m][v]);
            lesum[m][v] = red16_sum_f(lesum[m][v]);
        }

    // cross-wave combine (16 waves) through LDS
    if (l15 == 0) {
        #pragma unroll
        for (int m = 0; m < 4; m++)
            #pragma unroll
            for (int v = 0; v < 4; v++) {
                const int r = m * 16 + q * 4 + v;
                kred[w][r] = lkey[m][v]; ered[w][r] = lesum[m][v];
            }
    }
    __syncthreads();
    float lossreg = 0.f;
    if (t < 64) {
        unsigned bk = kred[0][t];
        float U = ered[0][t];
        #pragma unroll
        for (int ww = 1; ww < 16; ww++) {
            bk = max(bk, kred[ww][t]);
            U += ered[ww][t];
        }
        fidx[t] = 1023 - (int)(bk & 1023u);
        fU[t] = U;
        float a_rec = fkey_inv(bk);        // quantized a; s_min = -2a
        float z2 = 0.f;
        #pragma unroll
        for (int ds = 0; ds < 8; ds++) z2 += z2p[(t >> 4) * 8 + ds][t & 15];
        lossreg = z2 - 2.0f * a_rec;       // ||z-q||^2 = ||z||^2 + s_min
    }
    __syncthreads();

    // probs: column sums of e/U over the block's 64 rows
    float ps[4];
    #pragma unroll
    for (int nt = 0; nt < 4; nt++) ps[nt] = 0.f;
    #pragma unroll
    for (int m = 0; m < 4; m++)
        #pragma unroll
        for (int v = 0; v < 4; v++) {
            const float invU = 1.0f / fU[m * 16 + q * 4 + v];
            #pragma unroll
            for (int nt = 0; nt < 4; nt++) ps[nt] += acc[m][nt][v] * invU;
        }
    #pragma unroll
    for (int nt = 0; nt < 4; nt++) {
        ps[nt] += __shfl_xor(ps[nt], 16, 64);
        ps[nt] += __shfl_xor(ps[nt], 32, 64);
    }
    if (repmask < 0) pp[k0 + q * 16 + l15] = ps[q];          // store mode: unique col/block
    else             atomicAdd(&pp[k0 + q * 16 + l15], ps[q]);

    // quantized gather + store: wave w handles rows [4w, 4w+4)
    #pragma unroll
    for (int i = 0; i < 4; i++) {
        const int r  = w * 4 + i;
        const int am = fidx[r];
        f32x4 qv = *(const f32x4*)(cb + (size_t)am * DIM + ln * 4);
        *(f32x4*)(out_q + (size_t)(n0 + r) * DIM + ln * 4) = qv;
    }

    // loss: one atomic per block, spread over 64 slots
    if (w == 0) {
        #pragma unroll
        for (int off = 32; off; off >>= 1) lossreg += __shfl_down(lossreg, off, 64);
        if (ln == 0) atomicAdd(&lossR[blockIdx.x & 63], lossreg);
    }
}

// ---------------- K2: (optional codebook copy), probs reduce+mean+clip, vq_loss ----------------
// Store mode (R==NBLK): 16 blocks x 1024 threads; block b owns cols [64b,64b+64);
// wave w sums rows [64w,64w+64) COALESCED (lanes = consecutive cols), 16-way LDS combine.
__global__ __launch_bounds__(1024) void k_fin(const float* __restrict__ cb,
                                              const float* __restrict__ probs_part,
                                              const float* __restrict__ lossR,
                                              float* __restrict__ out,
                                              int R, int nLoss, int docopy) {
    const int t = threadIdx.x;
    const int g = blockIdx.x * 1024 + t;
    __shared__ float part[16][64];
    if (docopy && g < 262144) out[CB_OFF + g] = cb[g];
    if (R >= NBLK) {
        if (blockIdx.x < 16) {
            const int w  = t >> 6;
            const int ln = t & 63;
            const int col = blockIdx.x * 64 + ln;
            const float* p0 = probs_part + (size_t)(w * 64) * K_CODES + col;
            float a0 = 0.f, a1 = 0.f, a2 = 0.f, a3 = 0.f;
            #pragma unroll 4
            for (int r = 0; r < 64; r += 4) {
                a0 += p0[(size_t)(r + 0) * K_CODES];
                a1 += p0[(size_t)(r + 1) * K_CODES];
                a2 += p0[(size_t)(r + 2) * K_CODES];
                a3 += p0[(size_t)(r + 3) * K_CODES];
            }
            part[w][ln] = a0 + a1 + a2 + a3;
            __syncthreads();
            if (t < 64) {
                float p = 0.f;
                #pragma unroll
                for (int ww = 0; ww < 16; ww++) p += part[ww][t];
                p *= (1.0f / 65536.0f);
                p = fminf(fmaxf(p, 0.001f), 0.999f);
                out[PROBS_OFF + blockIdx.x * 64 + t] = p;
            }
        }
    } else if (g < K_CODES) {
        float a0 = 0.f, a1 = 0.f, a2 = 0.f, a3 = 0.f;
        if (R >= 4) {
            for (int r = 0; r < R; r += 4) {
                a0 += probs_part[(r + 0) * K_CODES + g];
                a1 += probs_part[(r + 1) * K_CODES + g];
                a2 += probs_part[(r + 2) * K_CODES + g];
                a3 += probs_part[(r + 3) * K_CODES + g];
            }
        } else {
            for (int r = 0; r < R; r++) a0 += probs_part[r * K_CODES + g];
        }
        float p = (a0 + a1 + a2 + a3) * (1.0f / 65536.0f);
        p = fminf(fmaxf(p, 0.001f), 0.999f);
        out[PROBS_OFF + g] = p;
    }
    if (g == 0) {
        float ls = 0.f;
        for (int r = 0; r < nLoss; r++) ls += lossR[r];
        out[LOSS_OFF] = ls * (1280.0f / 16777216.0f);   // 1.25*1024/(65536*256)
    }
}

extern "C" void kernel_launch(void* const* d_in, const int* in_sizes, int n_in,
                              void* d_out, int out_size, void* d_ws, size_t ws_size,
                              hipStream_t stream) {
    (void)in_sizes; (void)n_in; (void)out_size;
    const float* z  = (const float*)d_in[0];
    const float* cb = (const float*)d_in[1];
    float* out = (float*)d_out;

    float* c2 = (float*)d_ws;                 // 1024 floats

    // probs replicas: R=NBLK (store mode, no atomics) preferred; else atomic tiers.
    float *probs_part, *lossR;
    int R, nLoss, repmask;
    size_t used = 1024 * 4;
    auto fits = [&](int r) { return ws_size >= used + (size_t)(64 + r * 1024) * 4; };
    if      (fits(NBLK)) R = NBLK;
    else if (fits(64))   R = 64;
    else if (fits(16))   R = 16;
    else if (fits(4))    R = 4;
    else                 R = 0;
    const int storeMode = (R == NBLK);
    if (R) {
        lossR      = c2 + 1024;
        probs_part = lossR + 64;
        nLoss = 64;
        used += (size_t)(64 + (size_t)R * 1024) * 4;
        repmask = storeMode ? -1 : (R - 1);
    } else {
        probs_part = out + PROBS_OFF;
        lossR      = out + LOSS_OFF;
        R = 1; nLoss = 1; repmask = 0;
    }

    // bf16 frag-layout codebook, SPARSE 1024-short stride => true footprint 1 MB
    // (512 frags x 2KB). Reserve honestly; fallback region (out's 1MB cb slot) fits it
    // exactly, and k_fin rewrites that slot with the fp32 codebook afterwards.
    unsigned short* cbf;
    const size_t cbf_bytes = (size_t)512 * 1024 * 2;   // 1 MB
    int cbf_in_ws = (ws_size >= used + cbf_bytes);
    if (cbf_in_ws) cbf = (unsigned short*)((char*)d_ws + used);
    else           cbf = (unsigned short*)(out + CB_OFF);

    k_prep<<<dim3(64), dim3(512), 0, stream>>>(cb, c2, cbf, probs_part, lossR,
                                               out + CB_OFF, storeMode ? -NBLK : R * 1024,
                                               nLoss, cbf_in_ws);
    k_main<<<dim3(NBLK), dim3(1024), 0, stream>>>(z, cb, cbf, c2, out, probs_part,
                                                  lossR, repmask);
    const int fin_blocks = (!cbf_in_ws) ? 256 : (storeMode ? 16 : 1);
    k_fin<<<dim3(fin_blocks), dim3(1024), 0, stream>>>(cb, probs_part, lossR, out,
                                                       R, nLoss, !cbf_in_ws);
}